// Round 12
// baseline (2407.476 us; speedup 1.0000x reference)
//
#include <hip/hip_runtime.h>

#define B_    1024
#define T_    512
#define I_    16
#define H_    50
#define FC_   64
#define HALFW 28    // half of padded H (56)
#define HP    56    // H padded for float4 reads
#define R_    2     // batch rows per block

typedef float v2f __attribute__((ext_vector_type(2)));

__device__ __forceinline__ float frcp(float x)   { return __builtin_amdgcn_rcpf(x); }
__device__ __forceinline__ float sigm(float x)   { return frcp(1.0f + __expf(-x)); }
__device__ __forceinline__ float tanh_f(float x) { return 1.0f - 2.0f * frcp(1.0f + __expf(2.0f * x)); }
__device__ __forceinline__ v2f   mk2(float a, float b) { v2f r; r.x = a; r.y = b; return r; }

// FORCED packed fp32 FMA: acc = a*b + acc in ONE VOP3P instruction.
// (R11 evidence: __builtin_elementwise_fma on v2f lowers to 2x v_fma_f32 --
// the VALUBusy*dur arithmetic showed ~2.5x the hand-counted instruction
// stream. v_pk_fma_f32 exists on gfx90a+ / CDNA4.)
__device__ __forceinline__ v2f pk_fma(v2f a, v2f b, v2f acc) {
    asm("v_pk_fma_f32 %0, %1, %2, %0" : "+v"(acc) : "v"(a), "v"(b));
    return acc;
}

// intra-quad shuffles on the VALU (DPP quad_perm)
__device__ __forceinline__ float dpp_xor1(float v) {   // swap (0,1),(2,3)
    return __int_as_float(__builtin_amdgcn_update_dpp(0, __float_as_int(v), 0xB1, 0xF, 0xF, true));
}
__device__ __forceinline__ float dpp_xor2(float v) {   // swap (0,2),(1,3)
    return __int_as_float(__builtin_amdgcn_update_dpp(0, __float_as_int(v), 0x4E, 0xF, 0xF, true));
}

// one float4 of h against packed weight pair -> 2x v_pk_fma_f32
// (.xy / .zw of a ds_read_b128 float4 are even-aligned VGPR pairs: no moves)
#define PKDOT(acc, W, kk, hv) { acc = pk_fma(W[2*(kk)],   mk2(hv.x, hv.y), acc); \
                                acc = pk_fma(W[2*(kk)+1], mk2(hv.z, hv.w), acc); }
// 8-float x segment (two float4) against 4 packed weights
#define XDOT(acc, Wj, v0, v1) { acc = pk_fma(Wj[0], mk2(v0.x, v0.y), acc); \
                                acc = pk_fma(Wj[1], mk2(v0.z, v0.w), acc); \
                                acc = pk_fma(Wj[2], mk2(v1.x, v1.y), acc); \
                                acc = pk_fma(Wj[3], mk2(v1.z, v1.w), acc); }

// LAYER-PIPELINED (R11 structure, proven clean: VGPR=128, WRITE=8KB) with:
//  1. pk_fma inline asm (halves FMA instruction count)
//  2. R_=2, grid=512 -> 2 independent 512-thread blocks/CU -> 16 waves/CU
//     (4/SIMD) at the same <=128-reg allocation; waves_per_eu(4,4) keeps the
//     128-reg target while LIFTING the occupancy cap (R11's (2,2) max-capped
//     us at 2 waves/SIMD = no TLP to hide LDS/exp latency + barrier convoy).
// team 0 (tid<256) = layer 0 step t; team 1 = layer 1 step t-1; h handoff
// through ping-pong LDS; one barrier/step; L1 skips t=0, epilogue finishes.
__global__ __launch_bounds__(512) __attribute__((amdgpu_waves_per_eu(4, 4)))
void lstm_pipe2(
    const float* __restrict__ x,
    const float* __restrict__ w_ih0, const float* __restrict__ w_hh0,
    const float* __restrict__ b_ih0, const float* __restrict__ b_hh0,
    const float* __restrict__ w_ih1, const float* __restrict__ w_hh1,
    const float* __restrict__ b_ih1, const float* __restrict__ b_hh1,
    const float* __restrict__ fc1_w, const float* __restrict__ fc1_b,
    const float* __restrict__ fc2_w, const float* __restrict__ fc2_b,
    float* __restrict__ out)
{
    __shared__ float h0s[2][R_][HP];   // [pingpong][row][HP]
    __shared__ float h1s[2][R_][HP];

    const int tid  = threadIdx.x;
    const int team = tid >> 8;        // 0: layer 0, 1: layer 1
    const int lt   = tid & 255;
    const int u    = lt >> 2;
    const int qp   = (lt >> 1) & 1;
    const int s    = lt & 1;
    const bool gl  = lt < 4 * H_;     // 200 working lanes per team
    const int row0 = blockIdx.x * R_;

    // activation selectors for gate j=0 (qp0 -> i: sigmoid, qp1 -> g: tanh)
    const float qa = qp ? 2.0f : -1.0f;
    const float qb = qp ? 1.0f :  0.0f;
    const float qm = qp ? -2.0f : 1.0f;

    // ---- per-team weight registers (UNION, aliased): up to 112 regs ----
    // team0: wX = w_hh0 halves (14), wY[0..3] = w_ih0 (4 used)
    // team1: wX = w_ih1 halves (14), wY = w_hh1 halves (14)
    v2f wX[2][14], wY[2][14];
    float bias[2] = {0.f, 0.f};
    if (gl) {
        #pragma unroll
        for (int j = 0; j < 2; ++j) {
            const int g = (2 * qp + j) * H_ + u;
            if (team == 0) {
                #pragma unroll
                for (int k = 0; k < 14; ++k) {
                    const int j0 = s * HALFW + 2 * k, j1 = j0 + 1;
                    wX[j][k] = mk2(j0 < H_ ? w_hh0[g * H_ + j0] : 0.f,
                                   j1 < H_ ? w_hh0[g * H_ + j1] : 0.f);
                }
                #pragma unroll
                for (int k = 0; k < 4; ++k)
                    wY[j][k] = mk2(w_ih0[g * I_ + s * 8 + 2 * k],
                                   w_ih0[g * I_ + s * 8 + 2 * k + 1]);
                if (s == 0) bias[j] = b_ih0[g] + b_hh0[g];
            } else {
                #pragma unroll
                for (int k = 0; k < 14; ++k) {
                    const int j0 = s * HALFW + 2 * k, j1 = j0 + 1;
                    wX[j][k] = mk2(j0 < H_ ? w_ih1[g * H_ + j0] : 0.f,
                                   j1 < H_ ? w_ih1[g * H_ + j1] : 0.f);
                    wY[j][k] = mk2(j0 < H_ ? w_hh1[g * H_ + j0] : 0.f,
                                   j1 < H_ ? w_hh1[g * H_ + j1] : 0.f);
                }
                if (s == 0) bias[j] = b_ih1[g] + b_hh1[g];
            }
        }
    }

    if (tid < 2 * R_ * HP) { ((float*)h0s)[tid] = 0.f; ((float*)h1s)[tid] = 0.f; }
    float c[R_] = {0.f, 0.f};
    __syncthreads();

    // join -> activations -> gate exchange -> cell update (c replicated per quad)
    auto cell = [&](v2f P0, v2f P1, float& cc) -> float {
        float p0 = P0.x + P0.y;  p0 += dpp_xor1(p0);
        float p1 = P1.x + P1.y;  p1 += dpp_xor1(p1);
        float act0 = qb + qm * frcp(1.0f + __expf(qa * p0));  // i (qp0) or g (qp1)
        float act1 = sigm(p1);                                // f (qp0) or o (qp1)
        float ox0 = dpp_xor2(act0);
        float ox1 = dpp_xor2(act1);
        float gi = qp ? ox0 : act0;
        float gf = qp ? ox1 : act1;
        float gg = qp ? act0 : ox0;
        float go = qp ? act1 : ox1;
        cc = gf * cc + gi * gg;
        return go * tanh_f(cc);
    };

    // ---- main loop: L0 computes h0(t); L1 computes h1(t-1). One barrier. ----
    #pragma unroll 2
    for (int t = 0; t < T_; ++t) {
        const int pp = t & 1;
        if (team == 0) {
            if (gl) {
                float4 xv[R_][2];                    // x(t): issue all first
                #pragma unroll
                for (int r = 0; r < R_; ++r) {
                    const float* xp = x + ((size_t)(row0 + r) * T_ + t) * I_ + s * 8;
                    xv[r][0] = *(const float4*)xp;
                    xv[r][1] = *(const float4*)(xp + 4);
                }
                v2f P0[R_], P1[R_];
                #pragma unroll
                for (int r = 0; r < R_; ++r) {       // h0(t-1) part (LDS)
                    const float4* hp = (const float4*)(&h0s[pp][r][s * HALFW]);
                    P0[r] = mk2(bias[0], 0.f); P1[r] = mk2(bias[1], 0.f);
                    #pragma unroll
                    for (int k = 0; k < 7; ++k) {
                        float4 hv = hp[k];
                        PKDOT(P0[r], wX[0], k, hv); PKDOT(P1[r], wX[1], k, hv);
                    }
                }
                #pragma unroll
                for (int r = 0; r < R_; ++r) {       // x part (loads long done)
                    XDOT(P0[r], wY[0], xv[r][0], xv[r][1]);
                    XDOT(P1[r], wY[1], xv[r][0], xv[r][1]);
                    float hv = cell(P0[r], P1[r], c[r]);
                    if ((lt & 3) == 0) h0s[pp ^ 1][r][u] = hv;
                }
            }
        } else {
            if (gl && t > 0) {                       // L1 lags by one step
                #pragma unroll
                for (int r = 0; r < R_; ++r) {
                    const float4* h0p = (const float4*)(&h0s[pp][r][s * HALFW]);  // h0(t-1)
                    const float4* h1p = (const float4*)(&h1s[pp][r][s * HALFW]);  // h1(t-2)
                    v2f P0 = mk2(bias[0], 0.f), P1 = mk2(bias[1], 0.f);
                    #pragma unroll
                    for (int k = 0; k < 7; ++k) {
                        float4 hv = h0p[k];
                        PKDOT(P0, wX[0], k, hv); PKDOT(P1, wX[1], k, hv);
                    }
                    #pragma unroll
                    for (int k = 0; k < 7; ++k) {
                        float4 hv = h1p[k];
                        PKDOT(P0, wY[0], k, hv); PKDOT(P1, wY[1], k, hv);
                    }
                    float hv = cell(P0, P1, c[r]);
                    if ((lt & 3) == 0) h1s[pp ^ 1][r][u] = hv;
                }
            }
        }
        __syncthreads();
    }

    // ---- epilogue: L1 computes h1(T-1). h0(511) in h0s[0]; h1(510) in h1s[0]. ----
    if (team == 1 && gl) {
        #pragma unroll
        for (int r = 0; r < R_; ++r) {
            const float4* h0p = (const float4*)(&h0s[0][r][s * HALFW]);
            const float4* h1p = (const float4*)(&h1s[0][r][s * HALFW]);
            v2f P0 = mk2(bias[0], 0.f), P1 = mk2(bias[1], 0.f);
            #pragma unroll
            for (int k = 0; k < 7; ++k) {
                float4 hv = h0p[k];
                PKDOT(P0, wX[0], k, hv); PKDOT(P1, wX[1], k, hv);
            }
            #pragma unroll
            for (int k = 0; k < 7; ++k) {
                float4 hv = h1p[k];
                PKDOT(P0, wY[0], k, hv); PKDOT(P1, wY[1], k, hv);
            }
            float hv = cell(P0, P1, c[r]);
            if ((lt & 3) == 0) h1s[1][r][u] = hv;    // h1(T-1)
        }
    }
    __syncthreads();

    // ---- FC epilogue: wave r reduces row r ----
    if (tid < R_ * FC_) {
        const int r = tid >> 6, f = tid & 63;
        const float* hf = h1s[1][r];
        float a = fc1_b[f];
        #pragma unroll
        for (int j = 0; j < H_; ++j) a += fc1_w[f * H_ + j] * hf[j];
        float v = fmaxf(a, 0.f) * fc2_w[f];
        #pragma unroll
        for (int off = 1; off < FC_; off <<= 1) v += __shfl_xor(v, off);
        if (f == 0) out[row0 + r] = v + fc2_b[0];
    }
}

extern "C" void kernel_launch(void* const* d_in, const int* in_sizes, int n_in,
                              void* d_out, int out_size, void* d_ws, size_t ws_size,
                              hipStream_t stream) {
    const float* x     = (const float*)d_in[0];
    const float* w_ih0 = (const float*)d_in[1];
    const float* w_hh0 = (const float*)d_in[2];
    const float* b_ih0 = (const float*)d_in[3];
    const float* b_hh0 = (const float*)d_in[4];
    const float* w_ih1 = (const float*)d_in[5];
    const float* w_hh1 = (const float*)d_in[6];
    const float* b_ih1 = (const float*)d_in[7];
    const float* b_hh1 = (const float*)d_in[8];
    const float* fc1_w = (const float*)d_in[9];
    const float* fc1_b = (const float*)d_in[10];
    const float* fc2_w = (const float*)d_in[11];
    const float* fc2_b = (const float*)d_in[12];
    float* out = (float*)d_out;

    dim3 grid(B_ / R_), block(512);
    hipLaunchKernelGGL(lstm_pipe2, grid, block, 0, stream,
                       x, w_ih0, w_hh0, b_ih0, b_hh0,
                       w_ih1, w_hh1, b_ih1, b_hh1,
                       fc1_w, fc1_b, fc2_w, fc2_b, out);
}

// Round 13
// 1024.231 us; speedup vs baseline: 2.3505x; 2.3505x over previous
//
#include <hip/hip_runtime.h>

#define B_    1024
#define T_    512
#define I_    16
#define H_    50
#define FC_   64
#define HALFW 28    // half of padded H (56)
#define HP    56    // H padded for float4 reads
#define R_    2     // batch rows per block

typedef float v2f __attribute__((ext_vector_type(2)));

__device__ __forceinline__ float frcp(float x)   { return __builtin_amdgcn_rcpf(x); }
__device__ __forceinline__ float sigm(float x)   { return frcp(1.0f + __expf(-x)); }
__device__ __forceinline__ float tanh_f(float x) { return 1.0f - 2.0f * frcp(1.0f + __expf(2.0f * x)); }
__device__ __forceinline__ v2f   mk2(float a, float b) { v2f r; r.x = a; r.y = b; return r; }

// FORCED packed fp32 FMA: acc = a*b + acc in ONE VOP3P instruction.
__device__ __forceinline__ v2f pk_fma(v2f a, v2f b, v2f acc) {
    asm("v_pk_fma_f32 %0, %1, %2, %0" : "+v"(acc) : "v"(a), "v"(b));
    return acc;
}

// intra-quad shuffles on the VALU (DPP quad_perm)
__device__ __forceinline__ float dpp_xor1(float v) {   // swap (0,1),(2,3)
    return __int_as_float(__builtin_amdgcn_update_dpp(0, __float_as_int(v), 0xB1, 0xF, 0xF, true));
}
__device__ __forceinline__ float dpp_xor2(float v) {   // swap (0,2),(1,3)
    return __int_as_float(__builtin_amdgcn_update_dpp(0, __float_as_int(v), 0x4E, 0xF, 0xF, true));
}

// one float4 of h against packed weight pair -> 2x v_pk_fma_f32
#define PKDOT(acc, W, kk, hv) { acc = pk_fma(W[2*(kk)],   mk2(hv.x, hv.y), acc); \
                                acc = pk_fma(W[2*(kk)+1], mk2(hv.z, hv.w), acc); }
// 8-float x segment (two float4) against 4 packed weights
#define XDOT(acc, Wj, v0, v1) { acc = pk_fma(Wj[0], mk2(v0.x, v0.y), acc); \
                                acc = pk_fma(Wj[1], mk2(v0.z, v0.w), acc); \
                                acc = pk_fma(Wj[2], mk2(v1.x, v1.y), acc); \
                                acc = pk_fma(Wj[3], mk2(v1.z, v1.w), acc); }

// LAYER-PIPELINED + pk_fma + 2 blocks/CU.
// ONE-TOKEN FIX of R12: waves_per_eu (4,4) -> (2,4). Empirical allocator map:
// min=1 -> ~152 regs (AGPR-parks), min=2 -> 128 regs (CLEAN: R6/R11),
// min=4 -> 64 regs (R3/R12 scratch catastrophe, 53MB FETCH). min=2 keeps the
// 128-reg budget this structure fits (R11: VGPR=128, WRITE=8KB); max=4 lifts
// R11's occupancy cap so the SECOND 512-thread block co-resides at 128 regs
// (4 waves/SIMD), hiding LDS/exp latency + interleaving barrier convoys.
// team 0 (tid<256) = layer 0 step t; team 1 = layer 1 step t-1; h handoff
// through ping-pong LDS; one barrier/step; L1 skips t=0, epilogue finishes.
__global__ __launch_bounds__(512) __attribute__((amdgpu_waves_per_eu(2, 4)))
void lstm_pipe3(
    const float* __restrict__ x,
    const float* __restrict__ w_ih0, const float* __restrict__ w_hh0,
    const float* __restrict__ b_ih0, const float* __restrict__ b_hh0,
    const float* __restrict__ w_ih1, const float* __restrict__ w_hh1,
    const float* __restrict__ b_ih1, const float* __restrict__ b_hh1,
    const float* __restrict__ fc1_w, const float* __restrict__ fc1_b,
    const float* __restrict__ fc2_w, const float* __restrict__ fc2_b,
    float* __restrict__ out)
{
    __shared__ float h0s[2][R_][HP];   // [pingpong][row][HP]
    __shared__ float h1s[2][R_][HP];

    const int tid  = threadIdx.x;
    const int team = tid >> 8;        // 0: layer 0, 1: layer 1
    const int lt   = tid & 255;
    const int u    = lt >> 2;
    const int qp   = (lt >> 1) & 1;
    const int s    = lt & 1;
    const bool gl  = lt < 4 * H_;     // 200 working lanes per team
    const int row0 = blockIdx.x * R_;

    // activation selectors for gate j=0 (qp0 -> i: sigmoid, qp1 -> g: tanh)
    const float qa = qp ? 2.0f : -1.0f;
    const float qb = qp ? 1.0f :  0.0f;
    const float qm = qp ? -2.0f : 1.0f;

    // ---- per-team weight registers (UNION, aliased): up to 112 regs ----
    // team0: wX = w_hh0 halves (14), wY[0..3] = w_ih0 (4 used)
    // team1: wX = w_ih1 halves (14), wY = w_hh1 halves (14)
    v2f wX[2][14], wY[2][14];
    float bias[2] = {0.f, 0.f};
    if (gl) {
        #pragma unroll
        for (int j = 0; j < 2; ++j) {
            const int g = (2 * qp + j) * H_ + u;
            if (team == 0) {
                #pragma unroll
                for (int k = 0; k < 14; ++k) {
                    const int j0 = s * HALFW + 2 * k, j1 = j0 + 1;
                    wX[j][k] = mk2(j0 < H_ ? w_hh0[g * H_ + j0] : 0.f,
                                   j1 < H_ ? w_hh0[g * H_ + j1] : 0.f);
                }
                #pragma unroll
                for (int k = 0; k < 4; ++k)
                    wY[j][k] = mk2(w_ih0[g * I_ + s * 8 + 2 * k],
                                   w_ih0[g * I_ + s * 8 + 2 * k + 1]);
                if (s == 0) bias[j] = b_ih0[g] + b_hh0[g];
            } else {
                #pragma unroll
                for (int k = 0; k < 14; ++k) {
                    const int j0 = s * HALFW + 2 * k, j1 = j0 + 1;
                    wX[j][k] = mk2(j0 < H_ ? w_ih1[g * H_ + j0] : 0.f,
                                   j1 < H_ ? w_ih1[g * H_ + j1] : 0.f);
                    wY[j][k] = mk2(j0 < H_ ? w_hh1[g * H_ + j0] : 0.f,
                                   j1 < H_ ? w_hh1[g * H_ + j1] : 0.f);
                }
                if (s == 0) bias[j] = b_ih1[g] + b_hh1[g];
            }
        }
    }

    if (tid < 2 * R_ * HP) { ((float*)h0s)[tid] = 0.f; ((float*)h1s)[tid] = 0.f; }
    float c[R_] = {0.f, 0.f};
    __syncthreads();

    // join -> activations -> gate exchange -> cell update (c replicated per quad)
    auto cell = [&](v2f P0, v2f P1, float& cc) -> float {
        float p0 = P0.x + P0.y;  p0 += dpp_xor1(p0);
        float p1 = P1.x + P1.y;  p1 += dpp_xor1(p1);
        float act0 = qb + qm * frcp(1.0f + __expf(qa * p0));  // i (qp0) or g (qp1)
        float act1 = sigm(p1);                                // f (qp0) or o (qp1)
        float ox0 = dpp_xor2(act0);
        float ox1 = dpp_xor2(act1);
        float gi = qp ? ox0 : act0;
        float gf = qp ? ox1 : act1;
        float gg = qp ? act0 : ox0;
        float go = qp ? act1 : ox1;
        cc = gf * cc + gi * gg;
        return go * tanh_f(cc);
    };

    // ---- main loop: L0 computes h0(t); L1 computes h1(t-1). One barrier. ----
    #pragma unroll 2
    for (int t = 0; t < T_; ++t) {
        const int pp = t & 1;
        if (team == 0) {
            if (gl) {
                float4 xv[R_][2];                    // x(t): issue all first
                #pragma unroll
                for (int r = 0; r < R_; ++r) {
                    const float* xp = x + ((size_t)(row0 + r) * T_ + t) * I_ + s * 8;
                    xv[r][0] = *(const float4*)xp;
                    xv[r][1] = *(const float4*)(xp + 4);
                }
                v2f P0[R_], P1[R_];
                #pragma unroll
                for (int r = 0; r < R_; ++r) {       // h0(t-1) part (LDS)
                    const float4* hp = (const float4*)(&h0s[pp][r][s * HALFW]);
                    P0[r] = mk2(bias[0], 0.f); P1[r] = mk2(bias[1], 0.f);
                    #pragma unroll
                    for (int k = 0; k < 7; ++k) {
                        float4 hv = hp[k];
                        PKDOT(P0[r], wX[0], k, hv); PKDOT(P1[r], wX[1], k, hv);
                    }
                }
                #pragma unroll
                for (int r = 0; r < R_; ++r) {       // x part (loads long done)
                    XDOT(P0[r], wY[0], xv[r][0], xv[r][1]);
                    XDOT(P1[r], wY[1], xv[r][0], xv[r][1]);
                    float hv = cell(P0[r], P1[r], c[r]);
                    if ((lt & 3) == 0) h0s[pp ^ 1][r][u] = hv;
                }
            }
        } else {
            if (gl && t > 0) {                       // L1 lags by one step
                #pragma unroll
                for (int r = 0; r < R_; ++r) {
                    const float4* h0p = (const float4*)(&h0s[pp][r][s * HALFW]);  // h0(t-1)
                    const float4* h1p = (const float4*)(&h1s[pp][r][s * HALFW]);  // h1(t-2)
                    v2f P0 = mk2(bias[0], 0.f), P1 = mk2(bias[1], 0.f);
                    #pragma unroll
                    for (int k = 0; k < 7; ++k) {
                        float4 hv = h0p[k];
                        PKDOT(P0, wX[0], k, hv); PKDOT(P1, wX[1], k, hv);
                    }
                    #pragma unroll
                    for (int k = 0; k < 7; ++k) {
                        float4 hv = h1p[k];
                        PKDOT(P0, wY[0], k, hv); PKDOT(P1, wY[1], k, hv);
                    }
                    float hv = cell(P0, P1, c[r]);
                    if ((lt & 3) == 0) h1s[pp ^ 1][r][u] = hv;
                }
            }
        }
        __syncthreads();
    }

    // ---- epilogue: L1 computes h1(T-1). h0(511) in h0s[0]; h1(510) in h1s[0]. ----
    if (team == 1 && gl) {
        #pragma unroll
        for (int r = 0; r < R_; ++r) {
            const float4* h0p = (const float4*)(&h0s[0][r][s * HALFW]);
            const float4* h1p = (const float4*)(&h1s[0][r][s * HALFW]);
            v2f P0 = mk2(bias[0], 0.f), P1 = mk2(bias[1], 0.f);
            #pragma unroll
            for (int k = 0; k < 7; ++k) {
                float4 hv = h0p[k];
                PKDOT(P0, wX[0], k, hv); PKDOT(P1, wX[1], k, hv);
            }
            #pragma unroll
            for (int k = 0; k < 7; ++k) {
                float4 hv = h1p[k];
                PKDOT(P0, wY[0], k, hv); PKDOT(P1, wY[1], k, hv);
            }
            float hv = cell(P0, P1, c[r]);
            if ((lt & 3) == 0) h1s[1][r][u] = hv;    // h1(T-1)
        }
    }
    __syncthreads();

    // ---- FC epilogue: wave r reduces row r ----
    if (tid < R_ * FC_) {
        const int r = tid >> 6, f = tid & 63;
        const float* hf = h1s[1][r];
        float a = fc1_b[f];
        #pragma unroll
        for (int j = 0; j < H_; ++j) a += fc1_w[f * H_ + j] * hf[j];
        float v = fmaxf(a, 0.f) * fc2_w[f];
        #pragma unroll
        for (int off = 1; off < FC_; off <<= 1) v += __shfl_xor(v, off);
        if (f == 0) out[row0 + r] = v + fc2_b[0];
    }
}

extern "C" void kernel_launch(void* const* d_in, const int* in_sizes, int n_in,
                              void* d_out, int out_size, void* d_ws, size_t ws_size,
                              hipStream_t stream) {
    const float* x     = (const float*)d_in[0];
    const float* w_ih0 = (const float*)d_in[1];
    const float* w_hh0 = (const float*)d_in[2];
    const float* b_ih0 = (const float*)d_in[3];
    const float* b_hh0 = (const float*)d_in[4];
    const float* w_ih1 = (const float*)d_in[5];
    const float* w_hh1 = (const float*)d_in[6];
    const float* b_ih1 = (const float*)d_in[7];
    const float* b_hh1 = (const float*)d_in[8];
    const float* fc1_w = (const float*)d_in[9];
    const float* fc1_b = (const float*)d_in[10];
    const float* fc2_w = (const float*)d_in[11];
    const float* fc2_b = (const float*)d_in[12];
    float* out = (float*)d_out;

    dim3 grid(B_ / R_), block(512);
    hipLaunchKernelGGL(lstm_pipe3, grid, block, 0, stream,
                       x, w_ih0, w_hh0, b_ih0, b_hh0,
                       w_ih1, w_hh1, b_ih1, b_hh1,
                       fc1_w, fc1_b, fc2_w, fc2_b, out);
}